// Round 23
// baseline (182.678 us; speedup 1.0000x reference)
//
#include <hip/hip_runtime.h>
#include <hip/hip_bf16.h>

// GCN 2-layer encoder. CSR-gather aggregation + split-bf16 MFMA GEMMs.
// r23 = best-of: r20's fat (BM=64 gemm body, 1:4 csr stripes) + r22's fused scan +
// bf16 agg1 + bf16-A layer-2 gemm + BW-roofline gathers.

typedef __attribute__((ext_vector_type(4))) float f32x4;
typedef __attribute__((ext_vector_type(8))) short short8;

static __device__ __forceinline__ unsigned short f2bf(float f) {
    unsigned int u = __float_as_uint(f);
    u += 0x7FFF + ((u >> 16) & 1);          // round-to-nearest-even
    return (unsigned short)(u >> 16);
}
static __device__ __forceinline__ float bf2f(unsigned short h) {
    return __uint_as_float(((unsigned int)h) << 16);
}

static __device__ __forceinline__ void glds16(const void* g, void* l) {
    __builtin_amdgcn_global_load_lds(
        (const __attribute__((address_space(1))) void*)g,
        (__attribute__((address_space(3))) void*)l, 16, 0, 0);
}

// merged: image build (blocks 0..71) || degree histogram (blocks 72..)
// deg must be pre-zeroed (hipMemsetAsync).
__global__ void prep_deg(const float* __restrict__ W1, const float* __restrict__ W2,
                         unsigned short* __restrict__ I1, unsigned short* __restrict__ I2,
                         const int* __restrict__ dst, int* __restrict__ deg, int E) {
    const int bid = blockIdx.x;
    if (bid < 72) {
        int idx = bid * 256 + threadIdx.x;
        const int total1 = 16 * 1024;        // 16 kt x 2 pl x 4 slot x 128 col
        if (idx < total1) {
            int kt = idx >> 10, pl = (idx >> 9) & 1, slot = (idx >> 7) & 3, col = idx & 127;
            int k0 = kt * 32 + slot * 8;
#pragma unroll
            for (int j = 0; j < 8; j++) {
                int k = k0 + j;
                float v = (k < 500) ? W1[(size_t)k * 128 + col] : 0.f;
                unsigned short h = f2bf(v);
                I1[(size_t)idx * 8 + j] = pl ? f2bf(v - bf2f(h)) : h;
            }
        } else {
            int i2 = idx - total1;           // 4 kt x 2 pl x 4 slot x 64 col = 2048
            if (i2 < 2048) {
                int kt = i2 >> 9, pl = (i2 >> 8) & 1, slot = (i2 >> 6) & 3, col = i2 & 63;
                int k0 = kt * 32 + slot * 8;
#pragma unroll
                for (int j = 0; j < 8; j++) {
                    float v = W2[(size_t)(k0 + j) * 64 + col];
                    unsigned short h = f2bf(v);
                    I2[(size_t)i2 * 8 + j] = pl ? f2bf(v - bf2f(h)) : h;
                }
            }
        }
    } else {
        int e = (bid - 72) * 256 + threadIdx.x;
        if (e < E) atomicAdd(&deg[dst[e]], 1);
    }
}

// per-256-block totals
__global__ void scan_part(const int* __restrict__ deg, int* __restrict__ bsum, int N) {
    int tid = threadIdx.x, lane = tid & 63, wid = tid >> 6;
    int i = blockIdx.x * 256 + tid;
    int v = (i < N) ? deg[i] : 0;
#pragma unroll
    for (int off = 1; off < 64; off <<= 1) v += __shfl_xor(v, off, 64);
    __shared__ int ws[4];
    if (lane == 0) ws[wid] = v;
    __syncthreads();
    if (tid == 0) bsum[blockIdx.x] = ws[0] + ws[1] + ws[2] + ws[3];
}

// fused: inter-block base (sum of bsum[0..b)) + intra-block scan + cursor + dis
__global__ void scan_final(int* __restrict__ deg, const int* __restrict__ bsum,
                           int* __restrict__ rp, int* __restrict__ cursor, int N, int nb) {
    int tid = threadIdx.x, lane = tid & 63, wid = tid >> 6;
    int b = blockIdx.x;
    int i = b * 256 + tid;
    int v = (i < N) ? deg[i] : 0;
    int x = v;
#pragma unroll
    for (int off = 1; off < 64; off <<= 1) {
        int t = __shfl_up(x, off, 64);
        if (lane >= off) x += t;
    }
    __shared__ int wsum[4];
    if (lane == 63) wsum[wid] = x;
    int partial = 0;
    for (int p = lane; p < b; p += 64) partial += bsum[p];
#pragma unroll
    for (int off = 1; off < 64; off <<= 1) partial += __shfl_xor(partial, off, 64);
    __syncthreads();
    int base = partial;
    for (int ww = 0; ww < wid; ww++) base += wsum[ww];
    int ex = base + x - v;
    if (i < N) {
        rp[i] = ex;
        cursor[i] = ex;
        ((float*)deg)[i] = rsqrtf((float)(v + 1));
    }
    if (b == nb - 1 && tid == 255) rp[N] = base + x;   // total edges
}

// gemm body: C[M x BN] = A[M x K] @ B, split-bf16 MFMA, glds staging, WR=4 (wave tile 16xBN).
template<int BN, int KT, int KFULL>
__device__ __forceinline__ void gemm_body(
    int bid, unsigned char* sm,
    const float* __restrict__ A, const unsigned char* __restrict__ Wimg,
    unsigned short* __restrict__ C, int M, int K) {
    constexpr int ABYTES = 64 * 32 * 4;          // 8192
    constexpr int BBYTES = BN * 128;             // 16384 (BN=128)
    constexpr int STEP = ABYTES + BBYTES;
    constexpr int AINST = ABYTES / 1024;         // 8
    constexpr int BINST = BBYTES / 1024;         // 16
    constexpr int IPW = (AINST + BINST) / 4;     // 6
    constexpr int BIPW = BINST / 4;              // 4
    constexpr int NF = BN / 16;                  // 8

    const int tid = threadIdx.x, lane = tid & 63, w = tid >> 6;
    const int lrow = lane & 15, lq = lane >> 4;
    const int bm = bid * 64;

    f32x4 acc[NF] = {};

    float pr[8];
    {
        const int prow = tid >> 2, pk = (tid & 3) * 8;
        const int grow = bm + prow;
#pragma unroll
        for (int j = 0; j < 8; j++) {
            int k = KFULL * 32 + pk + j;
            pr[j] = (grow < M && k < K) ? A[(size_t)grow * K + k] : 0.f;
        }
    }

    auto STAGE = [&](int kt, int buf) {
        unsigned char* base = sm + buf * STEP;
#pragma unroll
        for (int j = 0; j < IPW; j++) {
            int g = w * IPW + j;
            if (g < AINST) {
                int srow = bm + lane; if (srow >= M) srow = M - 1;
                glds16(A + (size_t)srow * K + kt * 32 + g * 4, base + g * 1024);
            } else {
                int b = g - AINST;
                glds16(Wimg + (size_t)kt * BBYTES + (size_t)b * 1024 + lane * 16,
                       base + ABYTES + b * 1024);
            }
        }
    };
    auto STAGE_B = [&](int kt, int buf) {
        unsigned char* base = sm + buf * STEP;
#pragma unroll
        for (int j = 0; j < BIPW; j++) {
            int b = w * BIPW + j;
            glds16(Wimg + (size_t)kt * BBYTES + (size_t)b * 1024 + lane * 16,
                   base + ABYTES + b * 1024);
        }
    };
    auto REGWRITE = [&](int buf) {
        const int prow = tid >> 2, pk = (tid & 3) * 8;
        unsigned char* base = sm + buf * STEP;
        int s0 = pk >> 2;
        *(float4*)(base + s0 * 1024 + prow * 16) = make_float4(pr[0], pr[1], pr[2], pr[3]);
        *(float4*)(base + (s0 + 1) * 1024 + prow * 16) = make_float4(pr[4], pr[5], pr[6], pr[7]);
    };
    auto COMPUTE = [&](int buf) {
        const unsigned char* base = sm + buf * STEP;
        short8 ah, al;
        {
            int r = w * 16 + lrow;
            float4 f0 = *(const float4*)(base + (lq * 2) * 1024 + r * 16);
            float4 f1 = *(const float4*)(base + (lq * 2 + 1) * 1024 + r * 16);
            float fv[8] = {f0.x, f0.y, f0.z, f0.w, f1.x, f1.y, f1.z, f1.w};
#pragma unroll
            for (int e = 0; e < 8; e++) {
                unsigned short hu = f2bf(fv[e]);
                ah[e] = (short)hu;
                al[e] = (short)f2bf(fv[e] - bf2f(hu));
            }
        }
        short8 bh[NF], bl[NF];
#pragma unroll
        for (int n = 0; n < NF; n++) {
            int c = n * 16 + lrow;
            bh[n] = *(const short8*)(base + ABYTES + lq * (BN * 16) + c * 16);
            bl[n] = *(const short8*)(base + ABYTES + BBYTES / 2 + lq * (BN * 16) + c * 16);
        }
#pragma unroll
        for (int n = 0; n < NF; n++) {
            acc[n] = __builtin_amdgcn_mfma_f32_16x16x32_bf16(ah, bh[n], acc[n], 0, 0, 0);
            acc[n] = __builtin_amdgcn_mfma_f32_16x16x32_bf16(al, bh[n], acc[n], 0, 0, 0);
            acc[n] = __builtin_amdgcn_mfma_f32_16x16x32_bf16(ah, bl[n], acc[n], 0, 0, 0);
        }
    };

    STAGE(0, 0);
    __syncthreads();
    int cur = 0;
    for (int kt = 0; kt < KT; kt++) {
        if (kt + 1 < KT) {
            if (kt + 1 == KFULL) { STAGE_B(kt + 1, cur ^ 1); REGWRITE(cur ^ 1); }
            else STAGE(kt + 1, cur ^ 1);
        }
        COMPUTE(cur);
        __syncthreads();
        cur ^= 1;
    }

#pragma unroll
    for (int n = 0; n < NF; n++)
#pragma unroll
        for (int q = 0; q < 4; q++) {
            int row = bm + w * 16 + (lane >> 4) * 4 + q;
            int col = n * 16 + (lane & 15);
            if (row < M) C[(size_t)row * BN + col] = f2bf(acc[n][q]);
        }
}

// FAT: gemm1 BM=64 (stripe pos 0) || csr_fill (pos 1..4)
template<int BN, int KT, int KFULL>
__global__ __launch_bounds__(256) void fat_gemm_csr(
    const float* __restrict__ A, const unsigned char* __restrict__ Wimg,
    unsigned short* __restrict__ C, int M, int K,
    const int* __restrict__ src, const int* __restrict__ dst,
    int* __restrict__ cursor, int* __restrict__ csr_src, int E,
    int ngemm, int ncsr) {
    __shared__ unsigned char sm[2 * (8192 + BN * 128)];
    const int bid = blockIdx.x;
    const int stripe = bid / 5, pos = bid % 5;
    if (pos == 0) {
        if (stripe < ngemm)
            gemm_body<BN, KT, KFULL>(stripe, sm, A, Wimg, C, M, K);
    } else {
        int c = stripe * 4 + pos - 1;
        if (c < ncsr) {
            int e = c * 256 + threadIdx.x;
            if (e < E) {
                int p = atomicAdd(&cursor[dst[e]], 1);
                csr_src[p] = src[e];
            }
        }
    }
}

// ---- layer-2 gemm (BM=64, bf16 A exact, 2 MFMA/frag) ----
template<int BN, int KT>
__global__ __launch_bounds__(256) void gemm_glds_bf(
    const unsigned short* __restrict__ A, const unsigned char* __restrict__ Wimg,
    unsigned short* __restrict__ C, int M, int K) {
    constexpr int ABYTES = 64 * 32 * 2;          // 4096
    constexpr int BBYTES = BN * 128;             // 8192
    constexpr int STEP = ABYTES + BBYTES;
    constexpr int AINST = ABYTES / 1024;         // 4
    constexpr int BINST = BBYTES / 1024;         // 8
    constexpr int IPW = (AINST + BINST) / 4;     // 3
    constexpr int NF = BN / 16;                  // 4

    __shared__ unsigned char sm[2 * STEP];

    const int tid = threadIdx.x, lane = tid & 63, w = tid >> 6;
    const int lrow = lane & 15, lq = lane >> 4;
    const int bm = blockIdx.x * 64;

    f32x4 acc[NF] = {};

    auto STAGE = [&](int kt, int buf) {
        unsigned char* base = sm + buf * STEP;
#pragma unroll
        for (int j = 0; j < IPW; j++) {
            int g = w * IPW + j;
            if (g < AINST) {
                int srow = bm + lane; if (srow >= M) srow = M - 1;
                glds16(A + (size_t)srow * K + kt * 32 + g * 8, base + g * 1024);
            } else {
                int b = g - AINST;
                glds16(Wimg + (size_t)kt * BBYTES + (size_t)b * 1024 + lane * 16,
                       base + ABYTES + b * 1024);
            }
        }
    };
    auto COMPUTE = [&](int buf) {
        const unsigned char* base = sm + buf * STEP;
        short8 ah;
        {
            int r = w * 16 + lrow;
            ah = *(const short8*)(base + lq * 1024 + r * 16);
        }
        short8 bh[NF], bl[NF];
#pragma unroll
        for (int n = 0; n < NF; n++) {
            int c = n * 16 + lrow;
            bh[n] = *(const short8*)(base + ABYTES + lq * (BN * 16) + c * 16);
            bl[n] = *(const short8*)(base + ABYTES + BBYTES / 2 + lq * (BN * 16) + c * 16);
        }
#pragma unroll
        for (int n = 0; n < NF; n++) {
            acc[n] = __builtin_amdgcn_mfma_f32_16x16x32_bf16(ah, bh[n], acc[n], 0, 0, 0);
            acc[n] = __builtin_amdgcn_mfma_f32_16x16x32_bf16(ah, bl[n], acc[n], 0, 0, 0);
        }
    };

    STAGE(0, 0);
    __syncthreads();
    int cur = 0;
    for (int kt = 0; kt < KT; kt++) {
        if (kt + 1 < KT) STAGE(kt + 1, cur ^ 1);
        COMPUTE(cur);
        __syncthreads();
        cur ^= 1;
    }

#pragma unroll
    for (int n = 0; n < NF; n++)
#pragma unroll
        for (int q = 0; q < 4; q++) {
            int row = bm + w * 16 + (lane >> 4) * 4 + q;
            int col = n * 16 + (lane & 15);
            if (row < M) C[(size_t)row * BN + col] = f2bf(acc[n][q]);
        }
}

// gather for F=128 (bf16 h): half-wave per edge, 8 rows in flight. bf16 out (agg1).
__global__ __launch_bounds__(256) void gather128(
    const int* __restrict__ rp, const int* __restrict__ csr,
    const float* __restrict__ dis, const unsigned short* __restrict__ h,
    const float* __restrict__ bias, unsigned short* __restrict__ out, int Nn) {
    int n = (blockIdx.x * 256 + threadIdx.x) >> 6;
    int lane = threadIdx.x & 63;
    if (n >= Nn) return;
    const int hh = lane >> 5;
    const int l = lane & 31;
    int beg = rp[n], end = rp[n + 1];
    float4 a0 = {0,0,0,0}, a1 = {0,0,0,0}, a2 = {0,0,0,0}, a3 = {0,0,0,0};
    auto P = [&](int e, float4& a) {
        int s = csr[e];
        float w = dis[s];
        ushort4 v = *(const ushort4*)&h[(size_t)s * 128 + l * 4];
        a.x = fmaf(w, bf2f(v.x), a.x); a.y = fmaf(w, bf2f(v.y), a.y);
        a.z = fmaf(w, bf2f(v.z), a.z); a.w = fmaf(w, bf2f(v.w), a.w);
    };
    int j = beg + hh;
    for (; j + 6 < end; j += 8) { P(j, a0); P(j + 2, a1); P(j + 4, a2); P(j + 6, a3); }
    for (; j < end; j += 2) P(j, a0);
    float4 acc;
    acc.x = (a0.x + a1.x) + (a2.x + a3.x);
    acc.y = (a0.y + a1.y) + (a2.y + a3.y);
    acc.z = (a0.z + a1.z) + (a2.z + a3.z);
    acc.w = (a0.w + a1.w) + (a2.w + a3.w);
    acc.x += __shfl_xor(acc.x, 32);
    acc.y += __shfl_xor(acc.y, 32);
    acc.z += __shfl_xor(acc.z, 32);
    acc.w += __shfl_xor(acc.w, 32);
    float dn = dis[n];
    ushort4 hv = *(const ushort4*)&h[(size_t)n * 128 + l * 4];
    float4 b4 = *(const float4*)&bias[l * 4];
    if (hh == 0) {
        ushort4 o;
        o.x = f2bf(fmaxf(dn * (acc.x + dn * bf2f(hv.x)) + b4.x, 0.f));
        o.y = f2bf(fmaxf(dn * (acc.y + dn * bf2f(hv.y)) + b4.y, 0.f));
        o.z = f2bf(fmaxf(dn * (acc.z + dn * bf2f(hv.z)) + b4.z, 0.f));
        o.w = f2bf(fmaxf(dn * (acc.w + dn * bf2f(hv.w)) + b4.w, 0.f));
        *(ushort4*)&out[(size_t)n * 128 + l * 4] = o;
    }
}

// gather for F=64 (bf16 h): quarter-wave per edge, 8 rows in flight. f32 out.
__global__ __launch_bounds__(256) void gather64(
    const int* __restrict__ rp, const int* __restrict__ csr,
    const float* __restrict__ dis, const unsigned short* __restrict__ h,
    const float* __restrict__ bias, float* __restrict__ out, int Nn) {
    int n = (blockIdx.x * 256 + threadIdx.x) >> 6;
    int lane = threadIdx.x & 63;
    if (n >= Nn) return;
    const int q = lane >> 4;
    const int l = lane & 15;
    int beg = rp[n], end = rp[n + 1];
    float4 a0 = {0,0,0,0}, a1 = {0,0,0,0};
    auto P = [&](int e, float4& a) {
        int s = csr[e];
        float w = dis[s];
        ushort4 v = *(const ushort4*)&h[(size_t)s * 64 + l * 4];
        a.x = fmaf(w, bf2f(v.x), a.x); a.y = fmaf(w, bf2f(v.y), a.y);
        a.z = fmaf(w, bf2f(v.z), a.z); a.w = fmaf(w, bf2f(v.w), a.w);
    };
    int j = beg + q;
    for (; j + 4 < end; j += 8) { P(j, a0); P(j + 4, a1); }
    for (; j < end; j += 4) P(j, a0);
    float4 acc;
    acc.x = a0.x + a1.x; acc.y = a0.y + a1.y;
    acc.z = a0.z + a1.z; acc.w = a0.w + a1.w;
    acc.x += __shfl_xor(acc.x, 16); acc.x += __shfl_xor(acc.x, 32);
    acc.y += __shfl_xor(acc.y, 16); acc.y += __shfl_xor(acc.y, 32);
    acc.z += __shfl_xor(acc.z, 16); acc.z += __shfl_xor(acc.z, 32);
    acc.w += __shfl_xor(acc.w, 16); acc.w += __shfl_xor(acc.w, 32);
    float dn = dis[n];
    ushort4 hv = *(const ushort4*)&h[(size_t)n * 64 + l * 4];
    float4 b4 = *(const float4*)&bias[l * 4];
    float4 o;
    o.x = dn * (acc.x + dn * bf2f(hv.x)) + b4.x;
    o.y = dn * (acc.y + dn * bf2f(hv.y)) + b4.y;
    o.z = dn * (acc.z + dn * bf2f(hv.z)) + b4.z;
    o.w = dn * (acc.w + dn * bf2f(hv.w)) + b4.w;
    if (q == 0) *(float4*)&out[(size_t)n * 64 + l * 4] = o;
}

extern "C" void kernel_launch(void* const* d_in, const int* in_sizes, int n_in,
                              void* d_out, int out_size, void* d_ws, size_t ws_size,
                              hipStream_t stream) {
    const float* x  = (const float*)d_in[0];
    const int*   ei = (const int*)d_in[1];
    const float* W1 = (const float*)d_in[2];
    const float* b1 = (const float*)d_in[3];
    const float* W2 = (const float*)d_in[4];
    const float* b2 = (const float*)d_in[5];

    const int IN = 500, H = 128, OUT = 64;
    const int Nn = in_sizes[0] / IN;     // 50000
    const int E  = in_sizes[1] / 2;      // 800000
    const int* src  = ei;
    const int* dstp = ei + E;

    const int Npad = ((Nn + 63) / 64) * 64;
    const int nb   = (Nn + 255) / 256;
    const int ngemm = (Nn + 63) / 64;    // 782
    const int ncsr  = (E + 255) / 256;   // 3125

    // workspace layout (int units)
    int*   degdis  = (int*)d_ws;                 // N: int deg -> float dis in place
    int*   rp      = degdis + Npad;              // N+1
    int*   bsum    = rp + Npad + 64;             // 1024
    int*   boff    = bsum + 1024;                // 1024 (unused)
    int*   cursor  = boff + 1024;                // N
    int*   csr_src = cursor + Npad;              // E
    unsigned short* I1 = (unsigned short*)(csr_src + ((E + 63) / 64) * 64);  // 16 x 16KB
    unsigned short* I2 = I1 + 16 * 8192;         // 4 x 8KB
    unsigned short* h1u = I2 + 4 * 4096;         // Npad x 128 bf16
    unsigned short* agg1u = h1u + (size_t)Npad * H;  // Npad x 128 bf16
    unsigned short* h2u = h1u;                   // reuse after layer-1 gather
    float* dis     = (float*)degdis;
    float* out     = (float*)d_out;

    // ---- zero degree (memset node) + merged image-prep || degree histogram ----
    hipMemsetAsync(degdis, 0, (size_t)Nn * sizeof(int), stream);
    prep_deg<<<72 + ncsr, 256, 0, stream>>>(W1, W2, I1, I2, dstp, degdis, E);
    scan_part<<<nb, 256, 0, stream>>>(degdis, bsum, Nn);
    scan_final<<<nb, 256, 0, stream>>>(degdis, bsum, rp, cursor, Nn, nb);

    // ---- FAT: gemm1 (BM=64) || csr_fill, stripes 1:4 ----
    fat_gemm_csr<128, 16, 15><<<ngemm * 5, 256, 0, stream>>>(
        x, (const unsigned char*)I1, h1u, Nn, IN,
        src, dstp, cursor, csr_src, E, ngemm, ncsr);

    gather128<<<(Nn + 3) / 4, 256, 0, stream>>>(rp, csr_src, dis, h1u, b1, agg1u, Nn);

    // ---- layer 2 (bf16 A) ----
    gemm_glds_bf<64, 4><<<ngemm, 256, 0, stream>>>(
        agg1u, (const unsigned char*)I2, h2u, Nn, H);
    gather64<<<(Nn + 3) / 4, 256, 0, stream>>>(rp, csr_src, dis, h2u, b2, out, Nn);
}

// Round 24
// 179.971 us; speedup vs baseline: 1.0150x; 1.0150x over previous
//
#include <hip/hip_runtime.h>
#include <hip/hip_bf16.h>

// GCN 2-layer encoder. CSR-gather aggregation + split-bf16 MFMA GEMMs.
// FINAL (r22 config, best measured 179.98us): BM=32 fat (gemm1 || csr_fill 1:2 stripes),
// fused 2-kernel scan, bf16 h1/h2/agg1, bf16-A layer-2 gemm, BW-roofline gathers.

typedef __attribute__((ext_vector_type(4))) float f32x4;
typedef __attribute__((ext_vector_type(8))) short short8;

static __device__ __forceinline__ unsigned short f2bf(float f) {
    unsigned int u = __float_as_uint(f);
    u += 0x7FFF + ((u >> 16) & 1);          // round-to-nearest-even
    return (unsigned short)(u >> 16);
}
static __device__ __forceinline__ float bf2f(unsigned short h) {
    return __uint_as_float(((unsigned int)h) << 16);
}

static __device__ __forceinline__ void glds16(const void* g, void* l) {
    __builtin_amdgcn_global_load_lds(
        (const __attribute__((address_space(1))) void*)g,
        (__attribute__((address_space(3))) void*)l, 16, 0, 0);
}

// merged: image build (blocks 0..71) || degree histogram (blocks 72..)
// deg must be pre-zeroed (hipMemsetAsync).
__global__ void prep_deg(const float* __restrict__ W1, const float* __restrict__ W2,
                         unsigned short* __restrict__ I1, unsigned short* __restrict__ I2,
                         const int* __restrict__ dst, int* __restrict__ deg, int E) {
    const int bid = blockIdx.x;
    if (bid < 72) {
        int idx = bid * 256 + threadIdx.x;
        const int total1 = 16 * 1024;        // 16 kt x 2 pl x 4 slot x 128 col
        if (idx < total1) {
            int kt = idx >> 10, pl = (idx >> 9) & 1, slot = (idx >> 7) & 3, col = idx & 127;
            int k0 = kt * 32 + slot * 8;
#pragma unroll
            for (int j = 0; j < 8; j++) {
                int k = k0 + j;
                float v = (k < 500) ? W1[(size_t)k * 128 + col] : 0.f;
                unsigned short h = f2bf(v);
                I1[(size_t)idx * 8 + j] = pl ? f2bf(v - bf2f(h)) : h;
            }
        } else {
            int i2 = idx - total1;           // 4 kt x 2 pl x 4 slot x 64 col = 2048
            if (i2 < 2048) {
                int kt = i2 >> 9, pl = (i2 >> 8) & 1, slot = (i2 >> 6) & 3, col = i2 & 63;
                int k0 = kt * 32 + slot * 8;
#pragma unroll
                for (int j = 0; j < 8; j++) {
                    float v = W2[(size_t)(k0 + j) * 64 + col];
                    unsigned short h = f2bf(v);
                    I2[(size_t)i2 * 8 + j] = pl ? f2bf(v - bf2f(h)) : h;
                }
            }
        }
    } else {
        int e = (bid - 72) * 256 + threadIdx.x;
        if (e < E) atomicAdd(&deg[dst[e]], 1);
    }
}

// per-256-block totals
__global__ void scan_part(const int* __restrict__ deg, int* __restrict__ bsum, int N) {
    int tid = threadIdx.x, lane = tid & 63, wid = tid >> 6;
    int i = blockIdx.x * 256 + tid;
    int v = (i < N) ? deg[i] : 0;
#pragma unroll
    for (int off = 1; off < 64; off <<= 1) v += __shfl_xor(v, off, 64);
    __shared__ int ws[4];
    if (lane == 0) ws[wid] = v;
    __syncthreads();
    if (tid == 0) bsum[blockIdx.x] = ws[0] + ws[1] + ws[2] + ws[3];
}

// fused: inter-block base (sum of bsum[0..b)) + intra-block scan + cursor + dis
__global__ void scan_final(int* __restrict__ deg, const int* __restrict__ bsum,
                           int* __restrict__ rp, int* __restrict__ cursor, int N, int nb) {
    int tid = threadIdx.x, lane = tid & 63, wid = tid >> 6;
    int b = blockIdx.x;
    int i = b * 256 + tid;
    int v = (i < N) ? deg[i] : 0;
    int x = v;
#pragma unroll
    for (int off = 1; off < 64; off <<= 1) {
        int t = __shfl_up(x, off, 64);
        if (lane >= off) x += t;
    }
    __shared__ int wsum[4];
    if (lane == 63) wsum[wid] = x;
    // exclusive base over bsum[0..b), computed redundantly per wave (no extra barrier)
    int partial = 0;
    for (int p = lane; p < b; p += 64) partial += bsum[p];
#pragma unroll
    for (int off = 1; off < 64; off <<= 1) partial += __shfl_xor(partial, off, 64);
    __syncthreads();
    int base = partial;
    for (int ww = 0; ww < wid; ww++) base += wsum[ww];
    int ex = base + x - v;
    if (i < N) {
        rp[i] = ex;
        cursor[i] = ex;
        ((float*)deg)[i] = rsqrtf((float)(v + 1));
    }
    if (b == nb - 1 && tid == 255) rp[N] = base + x;   // total edges
}

// ---- gemm1 body, BM=32: 4 waves as 2 rowgrp x 2 colgrp (wave tile 16x64).
// A f32 [32x32] image (4KB, glds), B bf16 hi/lo image (16KB/step). Split-bf16, 3 MFMA/frag.
template<int KT, int KFULL>
__device__ __forceinline__ void gemm32_body(
    int bid, unsigned char* sm,
    const float* __restrict__ A, const unsigned char* __restrict__ Wimg,
    unsigned short* __restrict__ C, int M, int K) {
    constexpr int ABYTES = 4096, BBYTES = 16384, STEP = ABYTES + BBYTES;
    constexpr int NF = 4;

    const int tid = threadIdx.x, lane = tid & 63, w = tid >> 6;
    const int lrow = lane & 15, lq = lane >> 4;
    const int wrow = (w >> 1) * 16;
    const int wcol = (w & 1) * 64;
    const int bm = bid * 32;

    f32x4 acc[NF] = {};

    float pr[4];
    {
        const int prow = tid >> 3, pkq = tid & 7;
        const int grow = bm + prow;
#pragma unroll
        for (int j = 0; j < 4; j++) {
            int k = KFULL * 32 + pkq * 4 + j;
            pr[j] = (grow < M && k < K) ? A[(size_t)grow * K + k] : 0.f;
        }
    }

    auto STAGE = [&](int kt, int buf) {
        unsigned char* base = sm + buf * STEP;
#pragma unroll
        for (int j = 0; j < 5; j++) {
            int g = w * 5 + j;
            if (g < 4) {
                int row = lane >> 1;
                int srow = bm + row; if (srow >= M) srow = M - 1;
                int kq = (lane & 1) + g * 2;
                glds16(A + (size_t)srow * K + kt * 32 + kq * 4, base + g * 1024);
            } else {
                int b = g - 4;
                glds16(Wimg + (size_t)kt * BBYTES + (size_t)b * 1024 + lane * 16,
                       base + ABYTES + b * 1024);
            }
        }
    };
    auto STAGE_B = [&](int kt, int buf) {
        unsigned char* base = sm + buf * STEP;
#pragma unroll
        for (int j = 0; j < 4; j++) {
            int b = w * 4 + j;
            glds16(Wimg + (size_t)kt * BBYTES + (size_t)b * 1024 + lane * 16,
                   base + ABYTES + b * 1024);
        }
    };
    auto REGWRITE = [&](int buf) {
        const int prow = tid >> 3, pkq = tid & 7;
        unsigned char* base = sm + buf * STEP;
        *(float4*)(base + (pkq >> 1) * 1024 + (prow * 2 + (pkq & 1)) * 16) =
            make_float4(pr[0], pr[1], pr[2], pr[3]);
    };
    auto COMPUTE = [&](int buf) {
        const unsigned char* base = sm + buf * STEP;
        short8 ah, al;
        {
            int r = wrow + lrow;
            float4 f0 = *(const float4*)(base + lq * 1024 + r * 32);
            float4 f1 = *(const float4*)(base + lq * 1024 + r * 32 + 16);
            float fv[8] = {f0.x, f0.y, f0.z, f0.w, f1.x, f1.y, f1.z, f1.w};
#pragma unroll
            for (int e = 0; e < 8; e++) {
                unsigned short hu = f2bf(fv[e]);
                ah[e] = (short)hu;
                al[e] = (short)f2bf(fv[e] - bf2f(hu));
            }
        }
        short8 bh[NF], bl[NF];
#pragma unroll
        for (int n = 0; n < NF; n++) {
            int c = wcol + n * 16 + lrow;
            bh[n] = *(const short8*)(base + ABYTES + lq * 2048 + c * 16);
            bl[n] = *(const short8*)(base + ABYTES + 8192 + lq * 2048 + c * 16);
        }
#pragma unroll
        for (int n = 0; n < NF; n++) {
            acc[n] = __builtin_amdgcn_mfma_f32_16x16x32_bf16(ah, bh[n], acc[n], 0, 0, 0);
            acc[n] = __builtin_amdgcn_mfma_f32_16x16x32_bf16(al, bh[n], acc[n], 0, 0, 0);
            acc[n] = __builtin_amdgcn_mfma_f32_16x16x32_bf16(ah, bl[n], acc[n], 0, 0, 0);
        }
    };

    STAGE(0, 0);
    __syncthreads();
    int cur = 0;
    for (int kt = 0; kt < KT; kt++) {
        if (kt + 1 < KT) {
            if (kt + 1 == KFULL) { STAGE_B(kt + 1, cur ^ 1); REGWRITE(cur ^ 1); }
            else STAGE(kt + 1, cur ^ 1);
        }
        COMPUTE(cur);
        __syncthreads();
        cur ^= 1;
    }

#pragma unroll
    for (int n = 0; n < NF; n++)
#pragma unroll
        for (int q = 0; q < 4; q++) {
            int row = bm + wrow + (lane >> 4) * 4 + q;
            int col = wcol + n * 16 + (lane & 15);
            if (row < M) C[(size_t)row * 128 + col] = f2bf(acc[n][q]);
        }
}

// FAT: gemm1 BM=32 (stripe pos 0) || csr_fill (pos 1..2)
template<int KT, int KFULL>
__global__ __launch_bounds__(256) void fat_gemm_csr(
    const float* __restrict__ A, const unsigned char* __restrict__ Wimg,
    unsigned short* __restrict__ C, int M, int K,
    const int* __restrict__ src, const int* __restrict__ dst,
    int* __restrict__ cursor, int* __restrict__ csr_src, int E,
    int ngemm, int ncsr) {
    __shared__ unsigned char sm[2 * 20480];
    const int bid = blockIdx.x;
    const int stripe = bid / 3, pos = bid % 3;
    if (pos == 0) {
        if (stripe < ngemm)
            gemm32_body<KT, KFULL>(stripe, sm, A, Wimg, C, M, K);
    } else {
        int c = stripe * 2 + pos - 1;
        if (c < ncsr) {
            int e = c * 256 + threadIdx.x;
            if (e < E) {
                int p = atomicAdd(&cursor[dst[e]], 1);
                csr_src[p] = src[e];
            }
        }
    }
}

// ---- layer-2 gemm (BM=64, bf16 A exact, 2 MFMA/frag) ----
template<int BN, int KT>
__global__ __launch_bounds__(256) void gemm_glds_bf(
    const unsigned short* __restrict__ A, const unsigned char* __restrict__ Wimg,
    unsigned short* __restrict__ C, int M, int K) {
    constexpr int ABYTES = 64 * 32 * 2;          // 4096
    constexpr int BBYTES = BN * 128;             // 8192
    constexpr int STEP = ABYTES + BBYTES;
    constexpr int AINST = ABYTES / 1024;         // 4
    constexpr int BINST = BBYTES / 1024;         // 8
    constexpr int IPW = (AINST + BINST) / 4;     // 3
    constexpr int NF = BN / 16;                  // 4

    __shared__ unsigned char sm[2 * STEP];

    const int tid = threadIdx.x, lane = tid & 63, w = tid >> 6;
    const int lrow = lane & 15, lq = lane >> 4;
    const int bm = blockIdx.x * 64;

    f32x4 acc[NF] = {};

    auto STAGE = [&](int kt, int buf) {
        unsigned char* base = sm + buf * STEP;
#pragma unroll
        for (int j = 0; j < IPW; j++) {
            int g = w * IPW + j;
            if (g < AINST) {
                int srow = bm + lane; if (srow >= M) srow = M - 1;
                glds16(A + (size_t)srow * K + kt * 32 + g * 8, base + g * 1024);
            } else {
                int b = g - AINST;
                glds16(Wimg + (size_t)kt * BBYTES + (size_t)b * 1024 + lane * 16,
                       base + ABYTES + b * 1024);
            }
        }
    };
    auto COMPUTE = [&](int buf) {
        const unsigned char* base = sm + buf * STEP;
        short8 ah;
        {
            int r = w * 16 + lrow;
            ah = *(const short8*)(base + lq * 1024 + r * 16);
        }
        short8 bh[NF], bl[NF];
#pragma unroll
        for (int n = 0; n < NF; n++) {
            int c = n * 16 + lrow;
            bh[n] = *(const short8*)(base + ABYTES + lq * (BN * 16) + c * 16);
            bl[n] = *(const short8*)(base + ABYTES + BBYTES / 2 + lq * (BN * 16) + c * 16);
        }
#pragma unroll
        for (int n = 0; n < NF; n++) {
            acc[n] = __builtin_amdgcn_mfma_f32_16x16x32_bf16(ah, bh[n], acc[n], 0, 0, 0);
            acc[n] = __builtin_amdgcn_mfma_f32_16x16x32_bf16(ah, bl[n], acc[n], 0, 0, 0);
        }
    };

    STAGE(0, 0);
    __syncthreads();
    int cur = 0;
    for (int kt = 0; kt < KT; kt++) {
        if (kt + 1 < KT) STAGE(kt + 1, cur ^ 1);
        COMPUTE(cur);
        __syncthreads();
        cur ^= 1;
    }

#pragma unroll
    for (int n = 0; n < NF; n++)
#pragma unroll
        for (int q = 0; q < 4; q++) {
            int row = bm + w * 16 + (lane >> 4) * 4 + q;
            int col = n * 16 + (lane & 15);
            if (row < M) C[(size_t)row * BN + col] = f2bf(acc[n][q]);
        }
}

// gather for F=128 (bf16 h): half-wave per edge, 8 rows in flight. bf16 out (agg1).
__global__ __launch_bounds__(256) void gather128(
    const int* __restrict__ rp, const int* __restrict__ csr,
    const float* __restrict__ dis, const unsigned short* __restrict__ h,
    const float* __restrict__ bias, unsigned short* __restrict__ out, int Nn) {
    int n = (blockIdx.x * 256 + threadIdx.x) >> 6;
    int lane = threadIdx.x & 63;
    if (n >= Nn) return;
    const int hh = lane >> 5;
    const int l = lane & 31;
    int beg = rp[n], end = rp[n + 1];
    float4 a0 = {0,0,0,0}, a1 = {0,0,0,0}, a2 = {0,0,0,0}, a3 = {0,0,0,0};
    auto P = [&](int e, float4& a) {
        int s = csr[e];
        float w = dis[s];
        ushort4 v = *(const ushort4*)&h[(size_t)s * 128 + l * 4];
        a.x = fmaf(w, bf2f(v.x), a.x); a.y = fmaf(w, bf2f(v.y), a.y);
        a.z = fmaf(w, bf2f(v.z), a.z); a.w = fmaf(w, bf2f(v.w), a.w);
    };
    int j = beg + hh;
    for (; j + 6 < end; j += 8) { P(j, a0); P(j + 2, a1); P(j + 4, a2); P(j + 6, a3); }
    for (; j < end; j += 2) P(j, a0);
    float4 acc;
    acc.x = (a0.x + a1.x) + (a2.x + a3.x);
    acc.y = (a0.y + a1.y) + (a2.y + a3.y);
    acc.z = (a0.z + a1.z) + (a2.z + a3.z);
    acc.w = (a0.w + a1.w) + (a2.w + a3.w);
    acc.x += __shfl_xor(acc.x, 32);
    acc.y += __shfl_xor(acc.y, 32);
    acc.z += __shfl_xor(acc.z, 32);
    acc.w += __shfl_xor(acc.w, 32);
    float dn = dis[n];
    ushort4 hv = *(const ushort4*)&h[(size_t)n * 128 + l * 4];
    float4 b4 = *(const float4*)&bias[l * 4];
    if (hh == 0) {
        ushort4 o;
        o.x = f2bf(fmaxf(dn * (acc.x + dn * bf2f(hv.x)) + b4.x, 0.f));
        o.y = f2bf(fmaxf(dn * (acc.y + dn * bf2f(hv.y)) + b4.y, 0.f));
        o.z = f2bf(fmaxf(dn * (acc.z + dn * bf2f(hv.z)) + b4.z, 0.f));
        o.w = f2bf(fmaxf(dn * (acc.w + dn * bf2f(hv.w)) + b4.w, 0.f));
        *(ushort4*)&out[(size_t)n * 128 + l * 4] = o;
    }
}

// gather for F=64 (bf16 h): quarter-wave per edge, 8 rows in flight. f32 out.
__global__ __launch_bounds__(256) void gather64(
    const int* __restrict__ rp, const int* __restrict__ csr,
    const float* __restrict__ dis, const unsigned short* __restrict__ h,
    const float* __restrict__ bias, float* __restrict__ out, int Nn) {
    int n = (blockIdx.x * 256 + threadIdx.x) >> 6;
    int lane = threadIdx.x & 63;
    if (n >= Nn) return;
    const int q = lane >> 4;
    const int l = lane & 15;
    int beg = rp[n], end = rp[n + 1];
    float4 a0 = {0,0,0,0}, a1 = {0,0,0,0};
    auto P = [&](int e, float4& a) {
        int s = csr[e];
        float w = dis[s];
        ushort4 v = *(const ushort4*)&h[(size_t)s * 64 + l * 4];
        a.x = fmaf(w, bf2f(v.x), a.x); a.y = fmaf(w, bf2f(v.y), a.y);
        a.z = fmaf(w, bf2f(v.z), a.z); a.w = fmaf(w, bf2f(v.w), a.w);
    };
    int j = beg + q;
    for (; j + 4 < end; j += 8) { P(j, a0); P(j + 4, a1); }
    for (; j < end; j += 4) P(j, a0);
    float4 acc;
    acc.x = a0.x + a1.x; acc.y = a0.y + a1.y;
    acc.z = a0.z + a1.z; acc.w = a0.w + a1.w;
    acc.x += __shfl_xor(acc.x, 16); acc.x += __shfl_xor(acc.x, 32);
    acc.y += __shfl_xor(acc.y, 16); acc.y += __shfl_xor(acc.y, 32);
    acc.z += __shfl_xor(acc.z, 16); acc.z += __shfl_xor(acc.z, 32);
    acc.w += __shfl_xor(acc.w, 16); acc.w += __shfl_xor(acc.w, 32);
    float dn = dis[n];
    ushort4 hv = *(const ushort4*)&h[(size_t)n * 64 + l * 4];
    float4 b4 = *(const float4*)&bias[l * 4];
    float4 o;
    o.x = dn * (acc.x + dn * bf2f(hv.x)) + b4.x;
    o.y = dn * (acc.y + dn * bf2f(hv.y)) + b4.y;
    o.z = dn * (acc.z + dn * bf2f(hv.z)) + b4.z;
    o.w = dn * (acc.w + dn * bf2f(hv.w)) + b4.w;
    if (q == 0) *(float4*)&out[(size_t)n * 64 + l * 4] = o;
}

extern "C" void kernel_launch(void* const* d_in, const int* in_sizes, int n_in,
                              void* d_out, int out_size, void* d_ws, size_t ws_size,
                              hipStream_t stream) {
    const float* x  = (const float*)d_in[0];
    const int*   ei = (const int*)d_in[1];
    const float* W1 = (const float*)d_in[2];
    const float* b1 = (const float*)d_in[3];
    const float* W2 = (const float*)d_in[4];
    const float* b2 = (const float*)d_in[5];

    const int IN = 500, H = 128, OUT = 64;
    const int Nn = in_sizes[0] / IN;     // 50000
    const int E  = in_sizes[1] / 2;      // 800000
    const int* src  = ei;
    const int* dstp = ei + E;

    const int Npad = ((Nn + 63) / 64) * 64;
    const int nb   = (Nn + 255) / 256;
    const int ngemm1 = (Nn + 31) / 32;   // 1563
    const int ngemm2 = (Nn + 63) / 64;   // 782
    const int ncsr  = (E + 255) / 256;   // 3125

    // workspace layout (int units)
    int*   degdis  = (int*)d_ws;                 // N: int deg -> float dis in place
    int*   rp      = degdis + Npad;              // N+1
    int*   bsum    = rp + Npad + 64;             // 1024
    int*   boff    = bsum + 1024;                // 1024 (unused)
    int*   cursor  = boff + 1024;                // N
    int*   csr_src = cursor + Npad;              // E
    unsigned short* I1 = (unsigned short*)(csr_src + ((E + 63) / 64) * 64);  // 16 x 16KB
    unsigned short* I2 = I1 + 16 * 8192;         // 4 x 8KB
    unsigned short* h1u = I2 + 4 * 4096;         // Npad x 128 bf16
    unsigned short* agg1u = h1u + (size_t)Npad * H;  // Npad x 128 bf16
    unsigned short* h2u = h1u;                   // reuse after layer-1 gather
    float* dis     = (float*)degdis;
    float* out     = (float*)d_out;

    // ---- zero degree (memset node) + merged image-prep || degree histogram ----
    hipMemsetAsync(degdis, 0, (size_t)Nn * sizeof(int), stream);
    prep_deg<<<72 + ncsr, 256, 0, stream>>>(W1, W2, I1, I2, dstp, degdis, E);
    scan_part<<<nb, 256, 0, stream>>>(degdis, bsum, Nn);
    scan_final<<<nb, 256, 0, stream>>>(degdis, bsum, rp, cursor, Nn, nb);

    // ---- FAT: gemm1 (BM=32) || csr_fill, stripes 1:2 ----
    fat_gemm_csr<16, 15><<<ngemm1 * 3, 256, 0, stream>>>(
        x, (const unsigned char*)I1, h1u, Nn, IN,
        src, dstp, cursor, csr_src, E, ngemm1, ncsr);

    gather128<<<(Nn + 3) / 4, 256, 0, stream>>>(rp, csr_src, dis, h1u, b1, agg1u, Nn);

    // ---- layer 2 (bf16 A) ----
    gemm_glds_bf<64, 4><<<ngemm2, 256, 0, stream>>>(
        agg1u, (const unsigned char*)I2, h2u, Nn, H);
    gather64<<<(Nn + 3) / 4, 256, 0, stream>>>(rp, csr_src, dis, h2u, b2, out, Nn);
}